// Round 5
// baseline (212.976 us; speedup 1.0000x reference)
//
#include <hip/hip_runtime.h>

// Problem constants: x [B,S,F], Wq/Wk/Wv [F,D], out [B,S,D]
constexpr int Bc = 4, Sc = 4096, Fc = 512, Dc = 64;
constexpr int SPLIT = 4;            // split-K over keys in attention
constexpr int KT = 64;              // keys per tile
constexpr int TILES = (Sc / SPLIT) / KT;  // 16

typedef __attribute__((ext_vector_type(8)))  short  short8;   // 8 bf16
typedef __attribute__((ext_vector_type(4)))  float  float4v;
typedef __attribute__((ext_vector_type(16))) float  float16v;

__device__ inline unsigned short f2bf(float f) {
    union { float f; unsigned u; } v; v.f = f;
    unsigned r = v.u + 0x7FFF + ((v.u >> 16) & 1);   // RTNE
    return (unsigned short)(r >> 16);
}
__device__ inline unsigned pk2(float a, float b) {   // pack 2 floats -> 2 bf16 (RTNE)
    union { float f; unsigned u; } x, y; x.f = a; y.f = b;
    unsigned ra = x.u + 0x7FFF + ((x.u >> 16) & 1);
    unsigned rb = y.u + 0x7FFF + ((y.u >> 16) & 1);
    return (ra >> 16) | (rb & 0xFFFF0000u);
}

// ---------------------------------------------------------------------------
// Prep: Wt [192][512] bf16, transposed; rows 0-63 = Wq (x0.125),
// 64-127 = Wk, 128-191 = Wv.
// ---------------------------------------------------------------------------
__global__ __launch_bounds__(256) void prep_kernel(
    const float* __restrict__ Wq, const float* __restrict__ Wk,
    const float* __restrict__ Wv, unsigned short* __restrict__ Wt)
{
    int t = blockIdx.x * 256 + threadIdx.x;           // 768 threads
    int n = t >> 2, kc = (t & 3) * 128;
    const float* W = (n < 64) ? Wq : (n < 128) ? Wk : Wv;
    int nc = n & 63;
    float scale = (n < 64) ? 0.125f : 1.0f;
    for (int k = 0; k < 128; ++k)
        Wt[(size_t)n * Fc + kc + k] = f2bf(W[(size_t)(kc + k) * Dc + nc] * scale);
}

// ---------------------------------------------------------------------------
// QKV: grid 512 blocks, block 256 = 4 waves. Block owns 32 rows x 192 cols.
// Both x AND W staged through LDS with coalesced loads (W rows contiguous).
// Wave w owns 48 cols (3 n-tiles). B-frags ds_read_b128 from Ws.
// ---------------------------------------------------------------------------
__global__ __launch_bounds__(256) void qkv_kernel(
    const float* __restrict__ x, const unsigned short* __restrict__ Wt,
    unsigned short* __restrict__ Qb, unsigned short* __restrict__ Kb,
    unsigned short* __restrict__ Vtb)
{
    __shared__ __align__(16) unsigned short Xs[32][72];    // 4.6 KB
    __shared__ __align__(16) unsigned short Ws[192][72];   // 27.6 KB
    __shared__ __align__(16) unsigned short Ot[32][200];   // 12.8 KB bounce
    const int t = threadIdx.x;
    const int lane = t & 63, w = t >> 6;
    const int lm = lane & 15, quad = lane >> 4;
    const int row0 = blockIdx.x * 32;

    const int sr = t >> 3, sc = (t & 7) * 8;      // x staging: 32 x 64
    const int wr_ = t >> 2, wc = (t & 3) * 16;    // W staging: 64 rows/pass x 64

    float4 p0, p1;
    uint4 wv[3][2];
    auto load_x = [&](int k0) {
        const float* xp = x + (size_t)(row0 + sr) * Fc + k0 + sc;
        p0 = *(const float4*)xp;
        p1 = *(const float4*)(xp + 4);
    };
    auto load_w = [&](int k0) {
        #pragma unroll
        for (int j = 0; j < 3; ++j) {
            const unsigned short* wp = Wt + (size_t)(j * 64 + wr_) * Fc + k0 + wc;
            wv[j][0] = *(const uint4*)wp;
            wv[j][1] = *(const uint4*)(wp + 8);
        }
    };
    load_x(0); load_w(0);

    float4v acc[3][2];
    #pragma unroll
    for (int n = 0; n < 3; ++n)
        #pragma unroll
        for (int m = 0; m < 2; ++m) acc[n][m] = float4v{0.f, 0.f, 0.f, 0.f};

    for (int k0 = 0; k0 < Fc; k0 += 64) {
        __syncthreads();
        union { uint4 v; unsigned u[4]; } pk;
        pk.u[0] = pk2(p0.x, p0.y); pk.u[1] = pk2(p0.z, p0.w);
        pk.u[2] = pk2(p1.x, p1.y); pk.u[3] = pk2(p1.z, p1.w);
        *(uint4*)&Xs[sr][sc] = pk.v;
        #pragma unroll
        for (int j = 0; j < 3; ++j) {
            *(uint4*)&Ws[j * 64 + wr_][wc]     = wv[j][0];
            *(uint4*)&Ws[j * 64 + wr_][wc + 8] = wv[j][1];
        }
        __syncthreads();
        if (k0 + 64 < Fc) { load_x(k0 + 64); load_w(k0 + 64); }

        short8 af[2][2];
        #pragma unroll
        for (int m = 0; m < 2; ++m)
            #pragma unroll
            for (int h = 0; h < 2; ++h)
                af[m][h] = *(const short8*)&Xs[m * 16 + lm][h * 32 + quad * 8];

        #pragma unroll
        for (int n = 0; n < 3; ++n) {
            #pragma unroll
            for (int h = 0; h < 2; ++h) {
                short8 bf_ = *(const short8*)&Ws[(3 * w + n) * 16 + lm][h * 32 + quad * 8];
                #pragma unroll
                for (int m = 0; m < 2; ++m)
                    acc[n][m] = __builtin_amdgcn_mfma_f32_16x16x32_bf16(af[m][h], bf_, acc[n][m], 0, 0, 0);
            }
        }
    }

    // ---- epilogue: C-frags -> LDS bounce, coalesced out ----
    #pragma unroll
    for (int n = 0; n < 3; ++n)
        #pragma unroll
        for (int m = 0; m < 2; ++m)
            #pragma unroll
            for (int r = 0; r < 4; ++r)
                Ot[m * 16 + quad * 4 + r][(3 * w + n) * 16 + lm] = f2bf(acc[n][m][r]);
    __syncthreads();

    *(uint4*)&Qb[(size_t)(row0 + sr) * Dc + sc] = *(const uint4*)&Ot[sr][sc];
    *(uint4*)&Kb[(size_t)(row0 + sr) * Dc + sc] = *(const uint4*)&Ot[sr][64 + sc];
    {
        const int d = t >> 2, s8 = (t & 3) * 8;
        union { uint4 v; unsigned short s[8]; } tmp;
        #pragma unroll
        for (int j = 0; j < 8; ++j) tmp.s[j] = Ot[s8 + j][128 + d];
        const int bb = row0 >> 12, s0r = row0 & (Sc - 1);
        *(uint4*)&Vtb[((size_t)bb * Dc + d) * Sc + s0r + s8] = tmp.v;
    }
}

// ---------------------------------------------------------------------------
// Attention: S^T orientation, 32x32x16 MFMA, 32 q-rows per wave.
// Sequential 32-key halves (one score frag live) + shuffle-based P exchange
// (no P LDS round-trip). Block = 128 thr; grid (S/64, B, SPLIT) = 1024.
// ---------------------------------------------------------------------------
__global__ __launch_bounds__(128) void attn_kernel(
    const unsigned short* __restrict__ Qb, const unsigned short* __restrict__ Kb,
    const unsigned short* __restrict__ Vtb,
    float* __restrict__ Op, float* __restrict__ mp, float* __restrict__ lp)
{
    constexpr int PD = 72;
    __shared__ __align__(16) unsigned short Kt[64 * PD];   // [key][d]   9.2 KB
    __shared__ __align__(16) unsigned short Vt[64 * PD];   // [d][key]   9.2 KB

    const int t = threadIdx.x;
    const int lane = t & 63, w = t >> 6;
    const int l31 = lane & 31, lh = lane >> 5;
    const int b = blockIdx.y, z = blockIdx.z;
    const int q0 = blockIdx.x * 64 + w * 32;
    const size_t qkbase = (size_t)b * Sc * Dc;
    const size_t vbase  = (size_t)b * Dc * Sc;
    const int k0base = z * (Sc / SPLIT);

    // Q B-frags: B[k=d][n=qrow]
    short8 qf[4];
    #pragma unroll
    for (int c = 0; c < 4; ++c)
        qf[c] = *(const short8*)&Qb[qkbase + (size_t)(q0 + l31) * Dc + c * 16 + lh * 8];

    float16v O0, O1;
    #pragma unroll
    for (int r = 0; r < 16; ++r) { O0[r] = 0.f; O1[r] = 0.f; }
    float m_i = -1e30f, l_i = 0.f;

    const int skey = t >> 1, sd = (t & 1) * 32;
    uint4 kr[4], vr[4];
    auto load_tile = [&](int k0) {
        const unsigned short* kp = Kb + qkbase + (size_t)(k0 + skey) * Dc + sd;
        const unsigned short* vp = Vtb + vbase + (size_t)skey * Sc + k0 + sd;
        #pragma unroll
        for (int j = 0; j < 2; ++j) {
            kr[j] = *(const uint4*)(kp + j * 8);     kr[j + 2] = *(const uint4*)(kp + 16 + j * 8);
            vr[j] = *(const uint4*)(vp + j * 8);     vr[j + 2] = *(const uint4*)(vp + 16 + j * 8);
        }
    };
    load_tile(k0base);

    for (int kt = 0; kt < TILES; ++kt) {
        __syncthreads();
        #pragma unroll
        for (int j = 0; j < 4; ++j) {
            *(uint4*)&Kt[skey * PD + sd + j * 8] = kr[j];
            *(uint4*)&Vt[skey * PD + sd + j * 8] = vr[j];   // skey doubles as d
        }
        __syncthreads();
        if (kt + 1 < TILES) load_tile(k0base + (kt + 1) * KT);

        #pragma unroll
        for (int half = 0; half < 2; ++half) {
            // ---- S^T chunk = K[half].Q^T : keys half*32..+31 ----
            float16v s;
            #pragma unroll
            for (int r = 0; r < 16; ++r) s[r] = 0.f;
            #pragma unroll
            for (int c = 0; c < 4; ++c) {
                short8 a = *(const short8*)&Kt[(half * 32 + l31) * PD + c * 16 + lh * 8];
                s = __builtin_amdgcn_mfma_f32_32x32x16_bf16(a, qf[c], s, 0, 0, 0);
            }

            // ---- online softmax update (keys split across lane^32) ----
            float mt = -1e30f;
            #pragma unroll
            for (int r = 0; r < 16; ++r) mt = fmaxf(mt, s[r]);
            mt = fmaxf(mt, __shfl_xor(mt, 32));
            float mn = fmaxf(m_i, mt);
            float alpha = __expf(m_i - mn);
            m_i = mn;
            float rs = 0.f;
            #pragma unroll
            for (int r = 0; r < 16; ++r) {
                float p = __expf(s[r] - mn); s[r] = p; rs += p;
            }
            rs += __shfl_xor(rs, 32);
            l_i = l_i * alpha + rs;
            #pragma unroll
            for (int r = 0; r < 16; ++r) { O0[r] *= alpha; O1[r] *= alpha; }

            // ---- pack P, assemble B-frags via lane^32 exchange ----
            // lane holds P[key][qrow=l31], key = half*32 + (r&3)+8*(r>>2)+4*lh
            unsigned pu[8];
            #pragma unroll
            for (int g = 0; g < 4; ++g) {
                pu[2 * g]     = pk2(s[4 * g],     s[4 * g + 1]);
                pu[2 * g + 1] = pk2(s[4 * g + 2], s[4 * g + 3]);
            }
            #pragma unroll
            for (int c2 = 0; c2 < 2; ++c2) {
                unsigned s0_ = lh ? pu[4 * c2]     : pu[4 * c2 + 2];
                unsigned s1_ = lh ? pu[4 * c2 + 1] : pu[4 * c2 + 3];
                unsigned r0_ = __shfl_xor(s0_, 32);
                unsigned r1_ = __shfl_xor(s1_, 32);
                union { uint4 v; short8 s8; } pb;
                pb.v = lh == 0 ? make_uint4(pu[4 * c2], pu[4 * c2 + 1], r0_, r1_)
                               : make_uint4(r0_, r1_, pu[4 * c2 + 2], pu[4 * c2 + 3]);
                short8 va0 = *(const short8*)&Vt[(l31) * PD + half * 32 + c2 * 16 + lh * 8];
                short8 va1 = *(const short8*)&Vt[(32 + l31) * PD + half * 32 + c2 * 16 + lh * 8];
                O0 = __builtin_amdgcn_mfma_f32_32x32x16_bf16(va0, pb.s8, O0, 0, 0, 0);
                O1 = __builtin_amdgcn_mfma_f32_32x32x16_bf16(va1, pb.s8, O1, 0, 0, 0);
            }
        }
    }

    // ---- epilogue: bounce O^T through dead Kt/Vt, store coalesced fp32 ----
    __syncthreads();
    float* Of = (float*)(w == 0 ? Kt : Vt);         // 32 x 68 fp32, wave-private
    #pragma unroll
    for (int r = 0; r < 16; ++r) {
        int d0 = (r & 3) + 8 * (r >> 2) + 4 * lh;
        Of[l31 * 68 + d0]      = O0[r];
        Of[l31 * 68 + 32 + d0] = O1[r];
    }
    const size_t obase = ((size_t)(z * Bc + b) * Sc + q0) * Dc;
    const int qr = lane >> 4, c4 = (lane & 15) * 4;
    #pragma unroll
    for (int i = 0; i < 8; ++i) {
        int q = i * 4 + qr;
        *(float4*)&Op[obase + (size_t)q * Dc + c4] = *(const float4*)&Of[q * 68 + c4];
    }
    if (lane < 32) {
        int idx = (z * Bc + b) * Sc + q0 + l31;
        mp[idx] = m_i; lp[idx] = l_i;
    }
}

// ---------------------------------------------------------------------------
// Combine SPLIT partials: out = sum_z e^{m_z-M} O_z / sum_z e^{m_z-M} l_z
// ---------------------------------------------------------------------------
__global__ __launch_bounds__(256) void combine_kernel(
    const float* __restrict__ Op, const float* __restrict__ mp,
    const float* __restrict__ lp, float* __restrict__ out)
{
    const int BS = Bc * Sc;
    int tid = blockIdx.x * 256 + threadIdx.x;     // BS*16 threads
    int bq = tid >> 4, dc = (tid & 15) * 4;
    float m0 = mp[bq], m1 = mp[BS + bq], m2 = mp[2 * BS + bq], m3 = mp[3 * BS + bq];
    float M = fmaxf(fmaxf(m0, m1), fmaxf(m2, m3));
    float w0 = __expf(m0 - M), w1 = __expf(m1 - M), w2 = __expf(m2 - M), w3 = __expf(m3 - M);
    float L = w0 * lp[bq] + w1 * lp[BS + bq] + w2 * lp[2 * BS + bq] + w3 * lp[3 * BS + bq];
    float inv = 1.f / L;
    size_t o = (size_t)bq * Dc + dc;
    size_t stride = (size_t)BS * Dc;
    float4 p0 = *(const float4*)&Op[o];
    float4 p1 = *(const float4*)&Op[o + stride];
    float4 p2 = *(const float4*)&Op[o + 2 * stride];
    float4 p3 = *(const float4*)&Op[o + 3 * stride];
    float4 r;
    r.x = (w0 * p0.x + w1 * p1.x + w2 * p2.x + w3 * p3.x) * inv;
    r.y = (w0 * p0.y + w1 * p1.y + w2 * p2.y + w3 * p3.y) * inv;
    r.z = (w0 * p0.z + w1 * p1.z + w2 * p2.z + w3 * p3.z) * inv;
    r.w = (w0 * p0.w + w1 * p1.w + w2 * p2.w + w3 * p3.w) * inv;
    *(float4*)&out[o] = r;
}

// ---------------------------------------------------------------------------
extern "C" void kernel_launch(void* const* d_in, const int* in_sizes, int n_in,
                              void* d_out, int out_size, void* d_ws, size_t ws_size,
                              hipStream_t stream) {
    const float* x  = (const float*)d_in[0];
    const float* Wq = (const float*)d_in[1];
    const float* Wk = (const float*)d_in[2];
    const float* Wv = (const float*)d_in[3];
    float* out = (float*)d_out;

    char* p = (char*)d_ws;
    unsigned short* Wt  = (unsigned short*)p;  p += (size_t)192 * Fc * 2;      // 196 KB
    unsigned short* Qb  = (unsigned short*)p;  p += (size_t)Bc * Sc * Dc * 2;  // 2 MB
    unsigned short* Kb  = (unsigned short*)p;  p += (size_t)Bc * Sc * Dc * 2;  // 2 MB
    unsigned short* Vtb = (unsigned short*)p;  p += (size_t)Bc * Sc * Dc * 2;  // 2 MB
    float* Op = (float*)p;                     p += (size_t)SPLIT * Bc * Sc * Dc * 4; // 16.7 MB
    float* mp = (float*)p;                     p += (size_t)SPLIT * Bc * Sc * 4;      // 256 KB
    float* lp = (float*)p;

    prep_kernel<<<3, 256, 0, stream>>>(Wq, Wk, Wv, Wt);
    qkv_kernel<<<Bc * Sc / 32, 256, 0, stream>>>(x, Wt, Qb, Kb, Vtb);
    attn_kernel<<<dim3(Sc / 64, Bc, SPLIT), 128, 0, stream>>>(Qb, Kb, Vtb, Op, mp, lp);
    combine_kernel<<<(Bc * Sc * 16) / 256, 256, 0, stream>>>(Op, mp, lp, out);
}

// Round 7
// 169.147 us; speedup vs baseline: 1.2591x; 1.2591x over previous
//
#include <hip/hip_runtime.h>

// Problem constants: x [B,S,F], Wq/Wk/Wv [F,D], out [B,S,D]
constexpr int Bc = 4, Sc = 4096, Fc = 512, Dc = 64;
constexpr int SPLIT = 4;            // split-K over keys in attention
constexpr int KT = 64;              // keys per tile
constexpr int TILES = (Sc / SPLIT) / KT;  // 16

typedef __attribute__((ext_vector_type(8)))  short  short8;   // 8 bf16
typedef __attribute__((ext_vector_type(4)))  float  float4v;
typedef __attribute__((ext_vector_type(16))) float  float16v;

__device__ inline unsigned short f2bf(float f) {
    union { float f; unsigned u; } v; v.f = f;
    unsigned r = v.u + 0x7FFF + ((v.u >> 16) & 1);   // RTNE
    return (unsigned short)(r >> 16);
}
__device__ inline unsigned pk2(float a, float b) {   // pack 2 floats -> 2 bf16 (RTNE)
    union { float f; unsigned u; } x, y; x.f = a; y.f = b;
    unsigned ra = x.u + 0x7FFF + ((x.u >> 16) & 1);
    unsigned rb = y.u + 0x7FFF + ((y.u >> 16) & 1);
    return (ra >> 16) | (rb & 0xFFFF0000u);
}

// ---------------------------------------------------------------------------
// Cast: xb [B*S][512] bf16 (blocks 0..4095: 256 thr x 8 elem = 2048/block);
// Wt [192][512] bf16 transposed (blocks 4096..4143), rows 0-63 Wq (x0.125),
// 64-127 Wk, 128-191 Wv.
// ---------------------------------------------------------------------------
__global__ __launch_bounds__(256) void cast_kernel(
    const float* __restrict__ x, const float* __restrict__ Wq,
    const float* __restrict__ Wk, const float* __restrict__ Wv,
    unsigned short* __restrict__ xb, unsigned short* __restrict__ Wt)
{
    const int bx = blockIdx.x, t = threadIdx.x;
    if (bx < 4096) {
        size_t i = ((size_t)bx * 256 + t) * 8;      // covers 4096*2048 = 8.39M
        float4 a = *(const float4*)&x[i];
        float4 b = *(const float4*)&x[i + 4];
        uint4 o;
        o.x = pk2(a.x, a.y); o.y = pk2(a.z, a.w);
        o.z = pk2(b.x, b.y); o.w = pk2(b.z, b.w);
        *(uint4*)&xb[i] = o;
    } else {
        int wi = (bx - 4096) * 256 + t;          // 12288 threads
        int n = wi >> 6, kc = (wi & 63) * 8;     // 192 rows x 64 chunks
        const float* W = (n < 64) ? Wq : (n < 128) ? Wk : Wv;
        int nc = n & 63;
        float scale = (n < 64) ? 0.125f : 1.0f;
        #pragma unroll
        for (int j = 0; j < 8; ++j)
            Wt[(size_t)n * Fc + kc + j] = f2bf(W[(size_t)(kc + j) * Dc + nc] * scale);
    }
}

// ---------------------------------------------------------------------------
// QKV: grid 512, block 256 = 4 waves. Block = 32 rows x 192 cols (Q|K|V).
// Pure-bf16 hot loop: A-frags ds_read_b128 from Xs; B-frags from L2-hot Wt.
// ---------------------------------------------------------------------------
__global__ __launch_bounds__(256) void qkv_kernel(
    const unsigned short* __restrict__ xb, const unsigned short* __restrict__ Wt,
    unsigned short* __restrict__ Qb, unsigned short* __restrict__ Kb,
    unsigned short* __restrict__ Vtb)
{
    __shared__ __align__(16) unsigned short Xs[32][72];    // 4.6 KB
    __shared__ __align__(16) unsigned short Ot[32][200];   // 12.8 KB bounce
    const int t = threadIdx.x;
    const int lane = t & 63, w = t >> 6;
    const int lm = lane & 15, quad = lane >> 4;
    const int row0 = blockIdx.x * 32;
    const int sr = t >> 3, sc8 = (t & 7) * 8;   // 32 rows x 64 cols bf16

    uint4 xv;
    auto load_x = [&](int k0) {
        xv = *(const uint4*)&xb[(size_t)(row0 + sr) * Fc + k0 + sc8];
    };
    load_x(0);

    float4v acc[3][2];
    #pragma unroll
    for (int n = 0; n < 3; ++n)
        #pragma unroll
        for (int m = 0; m < 2; ++m) acc[n][m] = float4v{0.f, 0.f, 0.f, 0.f};

    for (int k0 = 0; k0 < Fc; k0 += 64) {
        __syncthreads();
        *(uint4*)&Xs[sr][sc8] = xv;
        __syncthreads();
        if (k0 + 64 < Fc) load_x(k0 + 64);

        short8 af[2][2];
        #pragma unroll
        for (int m = 0; m < 2; ++m)
            #pragma unroll
            for (int h = 0; h < 2; ++h)
                af[m][h] = *(const short8*)&Xs[m * 16 + lm][h * 32 + quad * 8];

        #pragma unroll
        for (int n = 0; n < 3; ++n) {
            const size_t wrow = (size_t)((3 * w + n) * 16 + lm) * Fc + k0;
            #pragma unroll
            for (int h = 0; h < 2; ++h) {
                short8 bf_ = *(const short8*)&Wt[wrow + h * 32 + quad * 8];
                #pragma unroll
                for (int m = 0; m < 2; ++m)
                    acc[n][m] = __builtin_amdgcn_mfma_f32_16x16x32_bf16(af[m][h], bf_, acc[n][m], 0, 0, 0);
            }
        }
    }

    // ---- epilogue: C-frags -> LDS bounce, coalesced out ----
    #pragma unroll
    for (int n = 0; n < 3; ++n)
        #pragma unroll
        for (int m = 0; m < 2; ++m)
            #pragma unroll
            for (int r = 0; r < 4; ++r)
                Ot[m * 16 + quad * 4 + r][(3 * w + n) * 16 + lm] = f2bf(acc[n][m][r]);
    __syncthreads();

    *(uint4*)&Qb[(size_t)(row0 + sr) * Dc + sc8] = *(const uint4*)&Ot[sr][sc8];
    *(uint4*)&Kb[(size_t)(row0 + sr) * Dc + sc8] = *(const uint4*)&Ot[sr][64 + sc8];
    {
        const int d = t >> 2, s8 = (t & 3) * 8;
        union { uint4 v; unsigned short s[8]; } tmp;
        #pragma unroll
        for (int j = 0; j < 8; ++j) tmp.s[j] = Ot[s8 + j][128 + d];
        const int bb = row0 >> 12, s0r = row0 & (Sc - 1);
        *(uint4*)&Vtb[((size_t)bb * Dc + d) * Sc + s0r + s8] = tmp.v;
    }
}

// ---------------------------------------------------------------------------
// Attention: 128 q-rows/block (4 waves x 32), SPLIT=4 over keys.
// grid (32, B, SPLIT) = 512 blocks x 256 thr = 8 waves/CU.
// S^T orientation, 32x32x16 MFMA; P^T via wave-private LDS round trip.
// ---------------------------------------------------------------------------
__global__ __launch_bounds__(256) void attn_kernel(
    const unsigned short* __restrict__ Qb, const unsigned short* __restrict__ Kb,
    const unsigned short* __restrict__ Vtb,
    float* __restrict__ Op, float* __restrict__ mp, float* __restrict__ lp)
{
    constexpr int PD = 72;
    __shared__ __align__(16) unsigned short Kt[64 * PD];     // [key][d]  9.2 KB
    __shared__ __align__(16) unsigned short Vt[64 * PD];     // [d][key]  9.2 KB
    __shared__ __align__(16) unsigned short Pt[4][32 * PD];  // wave-private 18.4 KB
    __shared__ __align__(16) float Ob[4][32 * 68];           // epilogue 34.8 KB

    const int t = threadIdx.x;
    const int lane = t & 63, w = t >> 6;
    const int l31 = lane & 31, lh = lane >> 5;
    const int b = blockIdx.y, z = blockIdx.z;
    const int q0 = blockIdx.x * 128 + w * 32;
    const size_t qkbase = (size_t)b * Sc * Dc;
    const size_t vbase  = (size_t)b * Dc * Sc;
    const int k0base = z * (Sc / SPLIT);

    // Q B-frags: B[k=d][n=qrow]
    short8 qf[4];
    #pragma unroll
    for (int c = 0; c < 4; ++c)
        qf[c] = *(const short8*)&Qb[qkbase + (size_t)(q0 + l31) * Dc + c * 16 + lh * 8];

    float16v O0, O1;
    #pragma unroll
    for (int r = 0; r < 16; ++r) { O0[r] = 0.f; O1[r] = 0.f; }
    float m_i = -1e30f, l_i = 0.f;

    // staging: 256 thr x 32B each for K and V (64x64 bf16 tiles)
    const int skey = t >> 2, sd = (t & 3) * 16;
    uint4 kr[2], vr[2];
    auto load_tile = [&](int k0) {
        const unsigned short* kp = Kb + qkbase + (size_t)(k0 + skey) * Dc + sd;
        const unsigned short* vp = Vtb + vbase + (size_t)skey * Sc + k0 + sd;
        kr[0] = *(const uint4*)kp;  kr[1] = *(const uint4*)(kp + 8);
        vr[0] = *(const uint4*)vp;  vr[1] = *(const uint4*)(vp + 8);
    };
    load_tile(k0base);

    for (int kt = 0; kt < TILES; ++kt) {
        __syncthreads();
        *(uint4*)&Kt[skey * PD + sd]     = kr[0];
        *(uint4*)&Kt[skey * PD + sd + 8] = kr[1];
        *(uint4*)&Vt[skey * PD + sd]     = vr[0];   // skey doubles as d
        *(uint4*)&Vt[skey * PD + sd + 8] = vr[1];
        __syncthreads();
        if (kt + 1 < TILES) load_tile(k0base + (kt + 1) * KT);

        // ---- S^T = K.Q^T ----
        float16v s0, s1;
        #pragma unroll
        for (int r = 0; r < 16; ++r) { s0[r] = 0.f; s1[r] = 0.f; }
        #pragma unroll
        for (int c = 0; c < 4; ++c) {
            short8 a0 = *(const short8*)&Kt[(l31) * PD + c * 16 + lh * 8];
            short8 a1 = *(const short8*)&Kt[(32 + l31) * PD + c * 16 + lh * 8];
            s0 = __builtin_amdgcn_mfma_f32_32x32x16_bf16(a0, qf[c], s0, 0, 0, 0);
            s1 = __builtin_amdgcn_mfma_f32_32x32x16_bf16(a1, qf[c], s1, 0, 0, 0);
        }

        // ---- online softmax: lane owns q-row l31; keys split lane^32 ----
        float mt = -1e30f;
        #pragma unroll
        for (int r = 0; r < 16; ++r) { mt = fmaxf(mt, s0[r]); mt = fmaxf(mt, s1[r]); }
        mt = fmaxf(mt, __shfl_xor(mt, 32));
        float mn = fmaxf(m_i, mt);
        float alpha = __expf(m_i - mn);
        m_i = mn;
        float rs = 0.f;
        #pragma unroll
        for (int r = 0; r < 16; ++r) {
            float p0 = __expf(s0[r] - mn); s0[r] = p0; rs += p0;
            float p1 = __expf(s1[r] - mn); s1[r] = p1; rs += p1;
        }
        rs += __shfl_xor(rs, 32);
        l_i = l_i * alpha + rs;

        // ---- P^T -> wave-private LDS (b64 packed) ----
        unsigned short* prow = &Pt[w][l31 * PD];
        #pragma unroll
        for (int g = 0; g < 4; ++g) {
            uint2 v;
            v.x = pk2(s0[4 * g], s0[4 * g + 1]); v.y = pk2(s0[4 * g + 2], s0[4 * g + 3]);
            *(uint2*)&prow[8 * g + 4 * lh] = v;
            v.x = pk2(s1[4 * g], s1[4 * g + 1]); v.y = pk2(s1[4 * g + 2], s1[4 * g + 3]);
            *(uint2*)&prow[32 + 8 * g + 4 * lh] = v;
        }

        #pragma unroll
        for (int r = 0; r < 16; ++r) { O0[r] *= alpha; O1[r] *= alpha; }

        // ---- O^T = V^T.P^T ----
        #pragma unroll
        for (int c = 0; c < 4; ++c) {
            short8 pb  = *(const short8*)&Pt[w][l31 * PD + c * 16 + lh * 8];
            short8 va0 = *(const short8*)&Vt[(l31) * PD + c * 16 + lh * 8];
            short8 va1 = *(const short8*)&Vt[(32 + l31) * PD + c * 16 + lh * 8];
            O0 = __builtin_amdgcn_mfma_f32_32x32x16_bf16(va0, pb, O0, 0, 0, 0);
            O1 = __builtin_amdgcn_mfma_f32_32x32x16_bf16(va1, pb, O1, 0, 0, 0);
        }
    }

    // ---- epilogue: wave-private LDS bounce, coalesced fp32 rows ----
    float* Of = Ob[w];                              // 32 x 68
    #pragma unroll
    for (int r = 0; r < 16; ++r) {
        int d0 = (r & 3) + 8 * (r >> 2) + 4 * lh;
        Of[l31 * 68 + d0]      = O0[r];
        Of[l31 * 68 + 32 + d0] = O1[r];
    }
    const size_t obase = ((size_t)(z * Bc + b) * Sc + q0) * Dc;
    const int qr = lane >> 4, c4 = (lane & 15) * 4;
    #pragma unroll
    for (int i = 0; i < 8; ++i) {
        int q = i * 4 + qr;
        *(float4*)&Op[obase + (size_t)q * Dc + c4] = *(const float4*)&Of[q * 68 + c4];
    }
    if (lane < 32) {
        int idx = (z * Bc + b) * Sc + q0 + l31;
        mp[idx] = m_i; lp[idx] = l_i;
    }
}

// ---------------------------------------------------------------------------
// Combine SPLIT partials: out = sum_z e^{m_z-M} O_z / sum_z e^{m_z-M} l_z
// ---------------------------------------------------------------------------
__global__ __launch_bounds__(256) void combine_kernel(
    const float* __restrict__ Op, const float* __restrict__ mp,
    const float* __restrict__ lp, float* __restrict__ out)
{
    const int BS = Bc * Sc;
    int tid = blockIdx.x * 256 + threadIdx.x;     // BS*16 threads
    int bq = tid >> 4, dc = (tid & 15) * 4;
    float m0 = mp[bq], m1 = mp[BS + bq], m2 = mp[2 * BS + bq], m3 = mp[3 * BS + bq];
    float M = fmaxf(fmaxf(m0, m1), fmaxf(m2, m3));
    float w0 = __expf(m0 - M), w1 = __expf(m1 - M), w2 = __expf(m2 - M), w3 = __expf(m3 - M);
    float L = w0 * lp[bq] + w1 * lp[BS + bq] + w2 * lp[2 * BS + bq] + w3 * lp[3 * BS + bq];
    float inv = 1.f / L;
    size_t o = (size_t)bq * Dc + dc;
    size_t stride = (size_t)BS * Dc;
    float4 p0 = *(const float4*)&Op[o];
    float4 p1 = *(const float4*)&Op[o + stride];
    float4 p2 = *(const float4*)&Op[o + 2 * stride];
    float4 p3 = *(const float4*)&Op[o + 3 * stride];
    float4 r;
    r.x = (w0 * p0.x + w1 * p1.x + w2 * p2.x + w3 * p3.x) * inv;
    r.y = (w0 * p0.y + w1 * p1.y + w2 * p2.y + w3 * p3.y) * inv;
    r.z = (w0 * p0.z + w1 * p1.z + w2 * p2.z + w3 * p3.z) * inv;
    r.w = (w0 * p0.w + w1 * p1.w + w2 * p2.w + w3 * p3.w) * inv;
    *(float4*)&out[o] = r;
}

// ---------------------------------------------------------------------------
extern "C" void kernel_launch(void* const* d_in, const int* in_sizes, int n_in,
                              void* d_out, int out_size, void* d_ws, size_t ws_size,
                              hipStream_t stream) {
    const float* x  = (const float*)d_in[0];
    const float* Wq = (const float*)d_in[1];
    const float* Wk = (const float*)d_in[2];
    const float* Wv = (const float*)d_in[3];
    float* out = (float*)d_out;

    // ws layout (~23.5 MB). xb and Op ALIAS (both 16.78 MB, disjoint lifetimes:
    // xb live cast->qkv; Op live attn->combine).
    char* p = (char*)d_ws;
    unsigned short* Wt  = (unsigned short*)p;  p += (size_t)192 * Fc * 2;        // 196 KB
    unsigned short* Qb  = (unsigned short*)p;  p += (size_t)Bc * Sc * Dc * 2;    // 2 MB
    unsigned short* Kb  = (unsigned short*)p;  p += (size_t)Bc * Sc * Dc * 2;    // 2 MB
    unsigned short* Vtb = (unsigned short*)p;  p += (size_t)Bc * Sc * Dc * 2;    // 2 MB
    float* mp = (float*)p;                     p += (size_t)SPLIT * Bc * Sc * 4; // 256 KB
    float* lp = (float*)p;                     p += (size_t)SPLIT * Bc * Sc * 4; // 256 KB
    unsigned short* xbuf = (unsigned short*)p; // 16.78 MB, aliased:
    float* Op = (float*)p;

    cast_kernel<<<4144, 256, 0, stream>>>(x, Wq, Wk, Wv, xbuf, Wt);
    qkv_kernel<<<Bc * Sc / 32, 256, 0, stream>>>(xbuf, Wt, Qb, Kb, Vtb);
    attn_kernel<<<dim3(Sc / 128, Bc, SPLIT), 256, 0, stream>>>(Qb, Kb, Vtb, Op, mp, lp);
    combine_kernel<<<(Bc * Sc * 16) / 256, 256, 0, stream>>>(Op, mp, lp, out);
}

// Round 8
// 152.174 us; speedup vs baseline: 1.3996x; 1.1115x over previous
//
#include <hip/hip_runtime.h>

// Problem constants: x [B,S,F], Wq/Wk/Wv [F,D], out [B,S,D]
constexpr int Bc = 4, Sc = 4096, Fc = 512, Dc = 64;
constexpr int SPLIT = 4;            // split-K over keys in attention
constexpr int KT = 64;              // keys per tile
constexpr int TILES = (Sc / SPLIT) / KT;  // 16

typedef __attribute__((ext_vector_type(8)))  short  short8;   // 8 bf16
typedef __attribute__((ext_vector_type(4)))  float  float4v;
typedef __attribute__((ext_vector_type(16))) float  float16v;

__device__ inline unsigned short f2bf(float f) {
    union { float f; unsigned u; } v; v.f = f;
    unsigned r = v.u + 0x7FFF + ((v.u >> 16) & 1);   // RTNE
    return (unsigned short)(r >> 16);
}
__device__ inline unsigned pk2(float a, float b) {   // pack 2 floats -> 2 bf16 (RTNE)
    union { float f; unsigned u; } x, y; x.f = a; y.f = b;
    unsigned ra = x.u + 0x7FFF + ((x.u >> 16) & 1);
    unsigned rb = y.u + 0x7FFF + ((y.u >> 16) & 1);
    return (ra >> 16) | (rb & 0xFFFF0000u);
}

// ---------------------------------------------------------------------------
// Prep: Wt [192][512] bf16 transposed; rows 0-63 Wq (x0.125), 64-127 Wk,
// 128-191 Wv. grid 48 x 256.
// ---------------------------------------------------------------------------
__global__ __launch_bounds__(256) void prep_kernel(
    const float* __restrict__ Wq, const float* __restrict__ Wk,
    const float* __restrict__ Wv, unsigned short* __restrict__ Wt)
{
    int wi = blockIdx.x * 256 + threadIdx.x;     // 12288 threads
    int n = wi >> 6, kc = (wi & 63) * 8;         // 192 rows x 64 chunks of 8
    const float* W = (n < 64) ? Wq : (n < 128) ? Wk : Wv;
    int nc = n & 63;
    float scale = (n < 64) ? 0.125f : 1.0f;
    #pragma unroll
    for (int j = 0; j < 8; ++j)
        Wt[(size_t)n * Fc + kc + j] = f2bf(W[(size_t)(kc + j) * Dc + nc] * scale);
}

// ---------------------------------------------------------------------------
// QKV: grid 512, block 256 = 4 waves. Block = 32 rows x 192 cols (Q|K|V).
// x read fp32 directly, packed to bf16 in-loop (no separate cast pass).
// A-frags ds_read_b128 from Xs; B-frags from L2-hot Wt.
// ---------------------------------------------------------------------------
__global__ __launch_bounds__(256) void qkv_kernel(
    const float* __restrict__ x, const unsigned short* __restrict__ Wt,
    unsigned short* __restrict__ Qb, unsigned short* __restrict__ Kb,
    unsigned short* __restrict__ Vtb)
{
    __shared__ __align__(16) unsigned short Xs[32][72];    // 4.6 KB
    __shared__ __align__(16) unsigned short Ot[32][200];   // 12.8 KB bounce
    const int t = threadIdx.x;
    const int lane = t & 63, w = t >> 6;
    const int lm = lane & 15, quad = lane >> 4;
    const int row0 = blockIdx.x * 32;
    const int sr = t >> 3, sc8 = (t & 7) * 8;   // 32 rows x 64 cols

    float4 p0, p1;
    auto load_x = [&](int k0) {
        const float* xp = x + (size_t)(row0 + sr) * Fc + k0 + sc8;
        p0 = *(const float4*)xp;
        p1 = *(const float4*)(xp + 4);
    };
    load_x(0);

    float4v acc[3][2];
    #pragma unroll
    for (int n = 0; n < 3; ++n)
        #pragma unroll
        for (int m = 0; m < 2; ++m) acc[n][m] = float4v{0.f, 0.f, 0.f, 0.f};

    for (int k0 = 0; k0 < Fc; k0 += 64) {
        __syncthreads();
        union { uint4 v; unsigned u[4]; } pk;
        pk.u[0] = pk2(p0.x, p0.y); pk.u[1] = pk2(p0.z, p0.w);
        pk.u[2] = pk2(p1.x, p1.y); pk.u[3] = pk2(p1.z, p1.w);
        *(uint4*)&Xs[sr][sc8] = pk.v;
        __syncthreads();
        if (k0 + 64 < Fc) load_x(k0 + 64);

        short8 af[2][2];
        #pragma unroll
        for (int m = 0; m < 2; ++m)
            #pragma unroll
            for (int h = 0; h < 2; ++h)
                af[m][h] = *(const short8*)&Xs[m * 16 + lm][h * 32 + quad * 8];

        #pragma unroll
        for (int n = 0; n < 3; ++n) {
            const size_t wrow = (size_t)((3 * w + n) * 16 + lm) * Fc + k0;
            #pragma unroll
            for (int h = 0; h < 2; ++h) {
                short8 bf_ = *(const short8*)&Wt[wrow + h * 32 + quad * 8];
                #pragma unroll
                for (int m = 0; m < 2; ++m)
                    acc[n][m] = __builtin_amdgcn_mfma_f32_16x16x32_bf16(af[m][h], bf_, acc[n][m], 0, 0, 0);
            }
        }
    }

    // ---- epilogue: C-frags -> LDS bounce, coalesced out ----
    #pragma unroll
    for (int n = 0; n < 3; ++n)
        #pragma unroll
        for (int m = 0; m < 2; ++m)
            #pragma unroll
            for (int r = 0; r < 4; ++r)
                Ot[m * 16 + quad * 4 + r][(3 * w + n) * 16 + lm] = f2bf(acc[n][m][r]);
    __syncthreads();

    *(uint4*)&Qb[(size_t)(row0 + sr) * Dc + sc8] = *(const uint4*)&Ot[sr][sc8];
    *(uint4*)&Kb[(size_t)(row0 + sr) * Dc + sc8] = *(const uint4*)&Ot[sr][64 + sc8];
    {
        const int d = t >> 2, s8 = (t & 3) * 8;
        union { uint4 v; unsigned short s[8]; } tmp;
        #pragma unroll
        for (int j = 0; j < 8; ++j) tmp.s[j] = Ot[s8 + j][128 + d];
        const int bb = row0 >> 12, s0r = row0 & (Sc - 1);
        *(uint4*)&Vtb[((size_t)bb * Dc + d) * Sc + s0r + s8] = tmp.v;
    }
}

// ---------------------------------------------------------------------------
// Attention: 128 q-rows/block (4 waves x 32), SPLIT=4 over keys.
// grid (32, B, SPLIT) = 512 blocks x 256 thr. LDS arena = 36.9 KB total
// (Kt/Vt/Pt overlaid by the epilogue bounce) -> 4 blocks/CU = 16 waves/CU.
// S^T orientation, 32x32x16 MFMA; P^T via wave-private LDS round trip.
// ---------------------------------------------------------------------------
__global__ __launch_bounds__(256) void attn_kernel(
    const unsigned short* __restrict__ Qb, const unsigned short* __restrict__ Kb,
    const unsigned short* __restrict__ Vtb,
    float* __restrict__ Op, float* __restrict__ mp, float* __restrict__ lp)
{
    constexpr int PD = 72;
    __shared__ __align__(16) char smem[36864];             // 36.9 KB arena
    unsigned short* Kt = (unsigned short*)smem;            // [key][d]  64*72
    unsigned short* Vt = (unsigned short*)(smem + 9216);   // [d][key]  64*72
    unsigned short* Pt = (unsigned short*)(smem + 18432);  // [wave][32*72]

    const int t = threadIdx.x;
    const int lane = t & 63, w = t >> 6;
    const int l31 = lane & 31, lh = lane >> 5;
    const int b = blockIdx.y, z = blockIdx.z;
    const int q0 = blockIdx.x * 128 + w * 32;
    const size_t qkbase = (size_t)b * Sc * Dc;
    const size_t vbase  = (size_t)b * Dc * Sc;
    const int k0base = z * (Sc / SPLIT);

    // Q B-frags: B[k=d][n=qrow]
    short8 qf[4];
    #pragma unroll
    for (int c = 0; c < 4; ++c)
        qf[c] = *(const short8*)&Qb[qkbase + (size_t)(q0 + l31) * Dc + c * 16 + lh * 8];

    float16v O0, O1;
    #pragma unroll
    for (int r = 0; r < 16; ++r) { O0[r] = 0.f; O1[r] = 0.f; }
    float m_i = -1e30f, l_i = 0.f;

    // staging: 256 thr x 32B each for K and V (64x64 bf16 tiles)
    const int skey = t >> 2, sd = (t & 3) * 16;
    uint4 kr[2], vr[2];
    auto load_tile = [&](int k0) {
        const unsigned short* kp = Kb + qkbase + (size_t)(k0 + skey) * Dc + sd;
        const unsigned short* vp = Vtb + vbase + (size_t)skey * Sc + k0 + sd;
        kr[0] = *(const uint4*)kp;  kr[1] = *(const uint4*)(kp + 8);
        vr[0] = *(const uint4*)vp;  vr[1] = *(const uint4*)(vp + 8);
    };
    load_tile(k0base);

    for (int kt = 0; kt < TILES; ++kt) {
        __syncthreads();
        *(uint4*)&Kt[skey * PD + sd]     = kr[0];
        *(uint4*)&Kt[skey * PD + sd + 8] = kr[1];
        *(uint4*)&Vt[skey * PD + sd]     = vr[0];   // skey doubles as d
        *(uint4*)&Vt[skey * PD + sd + 8] = vr[1];
        __syncthreads();
        if (kt + 1 < TILES) load_tile(k0base + (kt + 1) * KT);

        // ---- S^T = K.Q^T ----
        float16v s0, s1;
        #pragma unroll
        for (int r = 0; r < 16; ++r) { s0[r] = 0.f; s1[r] = 0.f; }
        #pragma unroll
        for (int c = 0; c < 4; ++c) {
            short8 a0 = *(const short8*)&Kt[(l31) * PD + c * 16 + lh * 8];
            short8 a1 = *(const short8*)&Kt[(32 + l31) * PD + c * 16 + lh * 8];
            s0 = __builtin_amdgcn_mfma_f32_32x32x16_bf16(a0, qf[c], s0, 0, 0, 0);
            s1 = __builtin_amdgcn_mfma_f32_32x32x16_bf16(a1, qf[c], s1, 0, 0, 0);
        }

        // ---- online softmax: lane owns q-row l31; keys split lane^32 ----
        float mt = -1e30f;
        #pragma unroll
        for (int r = 0; r < 16; ++r) { mt = fmaxf(mt, s0[r]); mt = fmaxf(mt, s1[r]); }
        mt = fmaxf(mt, __shfl_xor(mt, 32));
        float mn = fmaxf(m_i, mt);
        float alpha = __expf(m_i - mn);
        m_i = mn;
        float rs = 0.f;
        #pragma unroll
        for (int r = 0; r < 16; ++r) {
            float p0 = __expf(s0[r] - mn); s0[r] = p0; rs += p0;
            float p1 = __expf(s1[r] - mn); s1[r] = p1; rs += p1;
        }
        rs += __shfl_xor(rs, 32);
        l_i = l_i * alpha + rs;

        // ---- P^T -> wave-private LDS (b64 packed) ----
        unsigned short* prow = &Pt[w * 32 * PD + l31 * PD];
        #pragma unroll
        for (int g = 0; g < 4; ++g) {
            uint2 v;
            v.x = pk2(s0[4 * g], s0[4 * g + 1]); v.y = pk2(s0[4 * g + 2], s0[4 * g + 3]);
            *(uint2*)&prow[8 * g + 4 * lh] = v;
            v.x = pk2(s1[4 * g], s1[4 * g + 1]); v.y = pk2(s1[4 * g + 2], s1[4 * g + 3]);
            *(uint2*)&prow[32 + 8 * g + 4 * lh] = v;
        }

        #pragma unroll
        for (int r = 0; r < 16; ++r) { O0[r] *= alpha; O1[r] *= alpha; }

        // ---- O^T = V^T.P^T ----
        #pragma unroll
        for (int c = 0; c < 4; ++c) {
            short8 pb  = *(const short8*)&prow[c * 16 + lh * 8];
            short8 va0 = *(const short8*)&Vt[(l31) * PD + c * 16 + lh * 8];
            short8 va1 = *(const short8*)&Vt[(32 + l31) * PD + c * 16 + lh * 8];
            O0 = __builtin_amdgcn_mfma_f32_32x32x16_bf16(va0, pb, O0, 0, 0, 0);
            O1 = __builtin_amdgcn_mfma_f32_32x32x16_bf16(va1, pb, O1, 0, 0, 0);
        }
    }

    // ---- epilogue: overlay bounce on the (dead) arena, coalesced fp32 ----
    __syncthreads();                                   // all Kt/Vt/Pt reads done
    float* Of = (float*)(smem + w * 8704);             // 32 x 68 fp32 per wave
    #pragma unroll
    for (int r = 0; r < 16; ++r) {
        int d0 = (r & 3) + 8 * (r >> 2) + 4 * lh;
        Of[l31 * 68 + d0]      = O0[r];
        Of[l31 * 68 + 32 + d0] = O1[r];
    }
    const size_t obase = ((size_t)(z * Bc + b) * Sc + q0) * Dc;
    const int qr = lane >> 4, c4 = (lane & 15) * 4;
    #pragma unroll
    for (int i = 0; i < 8; ++i) {
        int q = i * 4 + qr;
        *(float4*)&Op[obase + (size_t)q * Dc + c4] = *(const float4*)&Of[q * 68 + c4];
    }
    if (lane < 32) {
        int idx = (z * Bc + b) * Sc + q0 + l31;
        mp[idx] = m_i; lp[idx] = l_i;
    }
}

// ---------------------------------------------------------------------------
// Combine SPLIT partials: out = sum_z e^{m_z-M} O_z / sum_z e^{m_z-M} l_z
// ---------------------------------------------------------------------------
__global__ __launch_bounds__(256) void combine_kernel(
    const float* __restrict__ Op, const float* __restrict__ mp,
    const float* __restrict__ lp, float* __restrict__ out)
{
    const int BS = Bc * Sc;
    int tid = blockIdx.x * 256 + threadIdx.x;     // BS*16 threads
    int bq = tid >> 4, dc = (tid & 15) * 4;
    float m0 = mp[bq], m1 = mp[BS + bq], m2 = mp[2 * BS + bq], m3 = mp[3 * BS + bq];
    float M = fmaxf(fmaxf(m0, m1), fmaxf(m2, m3));
    float w0 = __expf(m0 - M), w1 = __expf(m1 - M), w2 = __expf(m2 - M), w3 = __expf(m3 - M);
    float L = w0 * lp[bq] + w1 * lp[BS + bq] + w2 * lp[2 * BS + bq] + w3 * lp[3 * BS + bq];
    float inv = 1.f / L;
    size_t o = (size_t)bq * Dc + dc;
    size_t stride = (size_t)BS * Dc;
    float4 p0 = *(const float4*)&Op[o];
    float4 p1 = *(const float4*)&Op[o + stride];
    float4 p2 = *(const float4*)&Op[o + 2 * stride];
    float4 p3 = *(const float4*)&Op[o + 3 * stride];
    float4 r;
    r.x = (w0 * p0.x + w1 * p1.x + w2 * p2.x + w3 * p3.x) * inv;
    r.y = (w0 * p0.y + w1 * p1.y + w2 * p2.y + w3 * p3.y) * inv;
    r.z = (w0 * p0.z + w1 * p1.z + w2 * p2.z + w3 * p3.z) * inv;
    r.w = (w0 * p0.w + w1 * p1.w + w2 * p2.w + w3 * p3.w) * inv;
    *(float4*)&out[o] = r;
}

// ---------------------------------------------------------------------------
extern "C" void kernel_launch(void* const* d_in, const int* in_sizes, int n_in,
                              void* d_out, int out_size, void* d_ws, size_t ws_size,
                              hipStream_t stream) {
    const float* x  = (const float*)d_in[0];
    const float* Wq = (const float*)d_in[1];
    const float* Wk = (const float*)d_in[2];
    const float* Wv = (const float*)d_in[3];
    float* out = (float*)d_out;

    // ws layout (~23.5 MB)
    char* p = (char*)d_ws;
    unsigned short* Wt  = (unsigned short*)p;  p += (size_t)192 * Fc * 2;        // 196 KB
    unsigned short* Qb  = (unsigned short*)p;  p += (size_t)Bc * Sc * Dc * 2;    // 2 MB
    unsigned short* Kb  = (unsigned short*)p;  p += (size_t)Bc * Sc * Dc * 2;    // 2 MB
    unsigned short* Vtb = (unsigned short*)p;  p += (size_t)Bc * Sc * Dc * 2;    // 2 MB
    float* mp = (float*)p;                     p += (size_t)SPLIT * Bc * Sc * 4; // 256 KB
    float* lp = (float*)p;                     p += (size_t)SPLIT * Bc * Sc * 4; // 256 KB
    float* Op = (float*)p;                                                       // 16.7 MB

    prep_kernel<<<48, 256, 0, stream>>>(Wq, Wk, Wv, Wt);
    qkv_kernel<<<Bc * Sc / 32, 256, 0, stream>>>(x, Wt, Qb, Kb, Vtb);
    attn_kernel<<<dim3(Sc / 128, Bc, SPLIT), 256, 0, stream>>>(Qb, Kb, Vtb, Op, mp, lp);
    combine_kernel<<<(Bc * Sc * 16) / 256, 256, 0, stream>>>(Op, mp, lp, out);
}